// Round 4
// baseline (737.736 us; speedup 1.0000x reference)
//
#include <hip/hip_runtime.h>

// ---------------------------------------------------------------------------
// MultiHeadAttention_patch2: B*C = 262144 independent 4-token, 55-dim attns.
// All I/O is float32 (per the reference file's dtypes).
// Key identity (heads never split):
//   attn = softmax( xr M1 xr^T ),  M1 = scale * Wq^T Wk   (55x55)
//   out  = attn (xr P) + b,        P  = Wv^T Wfc^T        (55x55)
// Each sequence's 220 floats are contiguous in x; rearrange is a fixed
// permutation: local = p1*110 + p2*5 + h*10 + w,  token t=(p1,p2), d=(h,w).
//
// R1: removed runtime-indexed xreg[dp] (dynamic index -> scratch demotion).
// R2: weight rows padded 55 -> 56 floats (16B-aligned float4 stream).
// R3: no LDS for x; direct global loads/stores. Measured 467us, VALUBusy 26%,
//     occupancy 31%: the s_load weight stream (56 SGPRs/row, 112-SGPR budget)
//     forces a full lgkmcnt drain every iteration -> latency exposed.
// R4: weights staged in LDS (25 KB/block, 512-thread blocks). Uniform-address
//     ds_read_b128 broadcasts conflict-free into VGPRs, which the compiler
//     pipelines with partial lgkmcnt(N) waits interleaved into the FMA
//     stream — removes the per-iteration scalar-cache stall. Occupancy cap
//     unchanged (VGPR-bound, 4 waves/SIMD); stall per iteration shrinks.
// ---------------------------------------------------------------------------

// DPP quad-perm broadcast of lane j within each group of 4 lanes.
#define QB(v, ctrl) __int_as_float(__builtin_amdgcn_update_dpp( \
    0, __float_as_int(v), (ctrl), 0xf, 0xf, true))

#define PAD 56  // padded weight row stride (floats); 224 B = 14 aligned float4

typedef float vf4 __attribute__((ext_vector_type(4)));          // 16B-aligned
typedef float uvf4 __attribute__((ext_vector_type(4), aligned(4))); // 4B-aligned

// ws layout (fp32):
//   [0, 3080)        M1T[dp][0..55]  (row stride 56, [55] = 0)
//   [3080, 6160)     PT [dp][0..55]  (row stride 56, [55] = 0)
//   [6160, 6215)     bias[55]
__global__ void setup_weights(const float* __restrict__ wq,
                              const float* __restrict__ wk,
                              const float* __restrict__ wv,
                              const float* __restrict__ wfc,
                              const float* __restrict__ bfc,
                              float* __restrict__ ws) {
    int i = blockIdx.x * blockDim.x + threadIdx.x;
    if (i < 55 * PAD) {
        int dp = i / PAD, d = i % PAD;
        if (d < 55) {
            float m1 = 0.f, p = 0.f;
            for (int e = 0; e < 48; ++e) {
                m1 += wq[e * 55 + d] * wk[e * 55 + dp];
                p  += wv[e * 55 + d] * wfc[dp * 48 + e];
            }
            ws[dp * PAD + d]            = m1 * 0.14433756729740643f; // 1/sqrt(48)
            ws[55 * PAD + dp * PAD + d] = p;
        } else {
            ws[dp * PAD + d]            = 0.f; // zero pads: avoid 0*garbage=NaN
            ws[55 * PAD + dp * PAD + d] = 0.f;
        }
    }
    if (i < 55) ws[110 * PAD + i] = bfc[i];
}

__global__ void __launch_bounds__(512, 4)
attn_main(const float* __restrict__ x,
          const float* __restrict__ ws,
          float* __restrict__ out) {
    // 6216 floats = 24864 B of LDS: M1T | PT | bias (same layout as ws)
    __shared__ __align__(16) float wlds[6216];

    const int tid = threadIdx.x;

    // ---- stage weights into LDS once per block (one-time, coalesced) ----
    for (int i = tid; i < 6215; i += 512) wlds[i] = ws[i];
    __syncthreads();

    const float* __restrict__ M1L = wlds;
    const float* __restrict__ PTL = wlds + 55 * PAD;
    const float* __restrict__ BSL = wlds + 110 * PAD;

    const int t   = tid & 3;                                  // token in seq
    const size_t sq = ((size_t)blockIdx.x * 512 + tid) >> 2;  // sequence id
    const int tokoff = (t >> 1) * 110 + (t & 1) * 5;
    const float* __restrict__ xt = x   + sq * 220 + tokoff;
    float* __restrict__ ot       = out + sq * 220 + tokoff;

    // ---- own token's 55 features -> registers (constant indices only) ----
    // 11 runs of 5 contiguous floats, run h at byte offset h*40.
    float xreg[PAD];
    #pragma unroll
    for (int h = 0; h < 11; ++h) {
        const uvf4 v = *(const uvf4*)(xt + h * 10);
        xreg[5 * h + 0] = v.x;
        xreg[5 * h + 1] = v.y;
        xreg[5 * h + 2] = v.z;
        xreg[5 * h + 3] = v.w;
        xreg[5 * h + 4] = xt[h * 10 + 4];
    }
    xreg[55] = 0.f; // pad lane; weight pad is also 0

    // ---- phase A: la[t'] = sum_dp (xr[t]·M1T[dp]) * xr[t'][dp] ----
    float la0 = 0.f, la1 = 0.f, la2 = 0.f, la3 = 0.f;
    for (int h = 0; h < 11; ++h) {
        // own row h re-read from global (same addresses as the xreg load ->
        // guaranteed L1 hit). Keeps xreg free of runtime indices.
        const uvf4 c4 = *(const uvf4*)(xt + h * 10);
        const float c5 = xt[h * 10 + 4];
        const float xc[5] = {c4.x, c4.y, c4.z, c4.w, c5};

        #pragma unroll
        for (int w = 0; w < 5; ++w) {
            const int dp = h * 5 + w;
            // uniform LDS row -> broadcast ds_read_b128, pipelined by compiler
            const vf4* __restrict__ m4 = (const vf4*)(M1L + dp * PAD);
            float a0 = 0.f, a1 = 0.f, a2 = 0.f, a3 = 0.f;
            #pragma unroll
            for (int d4 = 0; d4 < 14; ++d4) {
                const vf4 mm = m4[d4];
                a0 = fmaf(xreg[4 * d4 + 0], mm.x, a0);
                a1 = fmaf(xreg[4 * d4 + 1], mm.y, a1);
                a2 = fmaf(xreg[4 * d4 + 2], mm.z, a2);
                a3 = fmaf(xreg[4 * d4 + 3], mm.w, a3);
            }
            const float t1 = (a0 + a1) + (a2 + a3);
            la0 = fmaf(t1, QB(xc[w], 0x00), la0);
            la1 = fmaf(t1, QB(xc[w], 0x55), la1);
            la2 = fmaf(t1, QB(xc[w], 0xAA), la2);
            la3 = fmaf(t1, QB(xc[w], 0xFF), la3);
        }
    }

    // ---- softmax over the 4 logits ----
    const float mx = fmaxf(fmaxf(la0, la1), fmaxf(la2, la3));
    const float e0 = __expf(la0 - mx), e1 = __expf(la1 - mx);
    const float e2 = __expf(la2 - mx), e3 = __expf(la3 - mx);
    const float inv = 1.0f / (e0 + e1 + e2 + e3);
    const float p0 = e0 * inv, p1 = e1 * inv, p2 = e2 * inv, p3 = e3 * inv;

    // ---- phase B: out[t][dp] = b[dp] + sum_t' p[t'] * (xr[t']·PT[dp]) ----
    for (int h = 0; h < 11; ++h) {
        float o[5];
        #pragma unroll
        for (int w = 0; w < 5; ++w) {
            const int dp = h * 5 + w;
            const vf4* __restrict__ pc4 = (const vf4*)(PTL + dp * PAD);
            float a0 = 0.f, a1 = 0.f, a2 = 0.f, a3 = 0.f;
            #pragma unroll
            for (int d4 = 0; d4 < 14; ++d4) {
                const vf4 mm = pc4[d4];
                a0 = fmaf(xreg[4 * d4 + 0], mm.x, a0);
                a1 = fmaf(xreg[4 * d4 + 1], mm.y, a1);
                a2 = fmaf(xreg[4 * d4 + 2], mm.z, a2);
                a3 = fmaf(xreg[4 * d4 + 3], mm.w, a3);
            }
            const float t2 = (a0 + a1) + (a2 + a3); // T2[own t][dp]
            float oo = BSL[dp]; // uniform LDS read
            oo = fmaf(p0, QB(t2, 0x00), oo);
            oo = fmaf(p1, QB(t2, 0x55), oo);
            oo = fmaf(p2, QB(t2, 0xAA), oo);
            oo = fmaf(p3, QB(t2, 0xFF), oo);
            o[w] = oo;
        }
        // direct store: align(4) float4 + scalar (L2 merges partial lines)
        uvf4 st;
        st.x = o[0]; st.y = o[1]; st.z = o[2]; st.w = o[3];
        *(uvf4*)(ot + h * 10) = st;
        ot[h * 10 + 4] = o[4];
    }
}

extern "C" void kernel_launch(void* const* d_in, const int* in_sizes, int n_in,
                              void* d_out, int out_size, void* d_ws, size_t ws_size,
                              hipStream_t stream) {
    const float* x   = (const float*)d_in[0];
    const float* wq  = (const float*)d_in[1];
    const float* wk  = (const float*)d_in[2];
    const float* wv  = (const float*)d_in[3];
    const float* wfc = (const float*)d_in[4];
    const float* bfc = (const float*)d_in[5];
    float* ws = (float*)d_ws; // needs 6215 floats = 24860 B

    const int nseq = out_size / 220;   // 262144
    const int nblk = nseq / 128;       // 2048 blocks of 512 threads (128 seqs)

    hipLaunchKernelGGL(setup_weights, dim3(13), dim3(256), 0, stream,
                       wq, wk, wv, wfc, bfc, ws);
    hipLaunchKernelGGL(attn_main, dim3(nblk), dim3(512), 0, stream,
                       x, ws, (float*)d_out);
}